// Round 1
// baseline (5175.882 us; speedup 1.0000x reference)
//
#include <hip/hip_runtime.h>
#include <math.h>

#define N_NODES 100000
#define F_IN    512
#define HIDDEN  64
#define N_CLASS 40
#define N_EDGES 3200000

// Harness doc: integer inputs -> const int*. Reference declares int64; if the
// absmax explodes, switch this to long long.
typedef int EIdx;

// ---------------- degree ----------------
__global__ __launch_bounds__(256) void init_deg_kernel(float* __restrict__ deg) {
    int i = blockIdx.x * 256 + threadIdx.x;
    if (i < N_NODES) deg[i] = 1.0f;  // self-loop
}

__global__ __launch_bounds__(256) void deg_count_kernel(const EIdx* __restrict__ dst,
                                                        float* __restrict__ deg) {
    int e = blockIdx.x * 256 + threadIdx.x;
    if (e < N_EDGES) atomicAdd(&deg[dst[e]], 1.0f);
}

__global__ __launch_bounds__(256) void rsqrt_kernel(float* __restrict__ deg) {
    int i = blockIdx.x * 256 + threadIdx.x;
    if (i < N_NODES) deg[i] = rsqrtf(deg[i]);  // deg >= 1 always
}

// ---------------- GEMM1: h = x @ W1  (one row per thread) ----------------
__global__ __launch_bounds__(256) void gemm1_kernel(const float* __restrict__ x,
                                                    const float* __restrict__ W,
                                                    float* __restrict__ h) {
    int r = blockIdx.x * 256 + threadIdx.x;
    if (r >= N_NODES) return;
    float acc[HIDDEN];
#pragma unroll
    for (int j = 0; j < HIDDEN; ++j) acc[j] = 0.0f;
    const float* xr = x + (size_t)r * F_IN;
    for (int k0 = 0; k0 < F_IN; k0 += 4) {
        float4 xv = *reinterpret_cast<const float4*>(xr + k0);
        const float* wk = W + (size_t)k0 * HIDDEN;   // W indexed wave-uniformly -> s_load
#pragma unroll
        for (int j = 0; j < HIDDEN; ++j) {
            acc[j] = fmaf(xv.x, wk[j], acc[j]);
            acc[j] = fmaf(xv.y, wk[HIDDEN + j], acc[j]);
            acc[j] = fmaf(xv.z, wk[2 * HIDDEN + j], acc[j]);
            acc[j] = fmaf(xv.w, wk[3 * HIDDEN + j], acc[j]);
        }
    }
    float* hr = h + (size_t)r * HIDDEN;
#pragma unroll
    for (int j = 0; j < HIDDEN; j += 4) {
        float4 o = {acc[j], acc[j + 1], acc[j + 2], acc[j + 3]};
        *reinterpret_cast<float4*>(hr + j) = o;
    }
}

// ---------------- layer-1 aggregation ----------------
// init: self-loop contribution agg = h[n] * dis[n]^2
__global__ __launch_bounds__(256) void agg1_init_kernel(const float* __restrict__ h,
                                                        const float* __restrict__ dis,
                                                        float* __restrict__ agg) {
    int tid = blockIdx.x * 256 + threadIdx.x;   // N_NODES*16 threads exactly
    int n = tid >> 4, c = tid & 15;
    float s = dis[n];
    float ss = s * s;
    float4 v = *reinterpret_cast<const float4*>(h + (size_t)n * HIDDEN + c * 4);
    float4 o = {v.x * ss, v.y * ss, v.z * ss, v.w * ss};
    *reinterpret_cast<float4*>(agg + (size_t)n * HIDDEN + c * 4) = o;
}

__global__ __launch_bounds__(256) void agg1_edge_kernel(const float* __restrict__ h,
                                                        const EIdx* __restrict__ src,
                                                        const EIdx* __restrict__ dst,
                                                        const float* __restrict__ dis,
                                                        float* __restrict__ agg) {
    int tid = blockIdx.x * 256 + threadIdx.x;   // N_EDGES*16 threads exactly
    int e = tid >> 4, c = tid & 15;
    int s = src[e], d = dst[e];
    float norm = dis[s] * dis[d];
    float4 v = *reinterpret_cast<const float4*>(h + (size_t)s * HIDDEN + c * 4);
    float* o = agg + (size_t)d * HIDDEN + c * 4;
    atomicAdd(o + 0, v.x * norm);
    atomicAdd(o + 1, v.y * norm);
    atomicAdd(o + 2, v.z * norm);
    atomicAdd(o + 3, v.w * norm);
}

// bias + relu, in place
__global__ __launch_bounds__(256) void relu_bias_kernel(float* __restrict__ agg,
                                                        const float* __restrict__ b) {
    int tid = blockIdx.x * 256 + threadIdx.x;   // N_NODES*16 exactly
    int n = tid >> 4, c = tid & 15;
    float* p = agg + (size_t)n * HIDDEN + c * 4;
    float4 v = *reinterpret_cast<const float4*>(p);
    float4 o = {fmaxf(v.x + b[c * 4 + 0], 0.f), fmaxf(v.y + b[c * 4 + 1], 0.f),
                fmaxf(v.z + b[c * 4 + 2], 0.f), fmaxf(v.w + b[c * 4 + 3], 0.f)};
    *reinterpret_cast<float4*>(p) = o;
}

// ---------------- GEMM2: h2 = out1 @ W2 (one row per thread) ----------------
__global__ __launch_bounds__(256) void gemm2_kernel(const float* __restrict__ x,
                                                    const float* __restrict__ W,
                                                    float* __restrict__ h) {
    int r = blockIdx.x * 256 + threadIdx.x;
    if (r >= N_NODES) return;
    float acc[N_CLASS];
#pragma unroll
    for (int j = 0; j < N_CLASS; ++j) acc[j] = 0.0f;
    const float* xr = x + (size_t)r * HIDDEN;
    for (int k0 = 0; k0 < HIDDEN; k0 += 4) {
        float4 xv = *reinterpret_cast<const float4*>(xr + k0);
        const float* wk = W + (size_t)k0 * N_CLASS;
#pragma unroll
        for (int j = 0; j < N_CLASS; ++j) {
            acc[j] = fmaf(xv.x, wk[j], acc[j]);
            acc[j] = fmaf(xv.y, wk[N_CLASS + j], acc[j]);
            acc[j] = fmaf(xv.z, wk[2 * N_CLASS + j], acc[j]);
            acc[j] = fmaf(xv.w, wk[3 * N_CLASS + j], acc[j]);
        }
    }
    float* hr = h + (size_t)r * N_CLASS;
#pragma unroll
    for (int j = 0; j < N_CLASS; j += 4) {
        float4 o = {acc[j], acc[j + 1], acc[j + 2], acc[j + 3]};
        *reinterpret_cast<float4*>(hr + j) = o;
    }
}

// ---------------- layer-2 aggregation (into x_out) ----------------
// init: self-loop + bias
__global__ __launch_bounds__(256) void agg2_init_kernel(const float* __restrict__ h2,
                                                        const float* __restrict__ dis,
                                                        const float* __restrict__ b,
                                                        float* __restrict__ xout) {
    int tid = blockIdx.x * 256 + threadIdx.x;
    if (tid >= N_NODES * 10) return;
    int n = tid / 10, c = tid % 10;
    float s = dis[n];
    float ss = s * s;
    float4 v = *reinterpret_cast<const float4*>(h2 + (size_t)n * N_CLASS + c * 4);
    float4 o = {v.x * ss + b[c * 4 + 0], v.y * ss + b[c * 4 + 1],
                v.z * ss + b[c * 4 + 2], v.w * ss + b[c * 4 + 3]};
    *reinterpret_cast<float4*>(xout + (size_t)n * N_CLASS + c * 4) = o;
}

__global__ __launch_bounds__(256) void agg2_edge_kernel(const float* __restrict__ h2,
                                                        const EIdx* __restrict__ src,
                                                        const EIdx* __restrict__ dst,
                                                        const float* __restrict__ dis,
                                                        float* __restrict__ xout) {
    int tid = blockIdx.x * 256 + threadIdx.x;   // N_EDGES*10 exactly
    int e = tid / 10, c = tid % 10;
    int s = src[e], d = dst[e];
    float norm = dis[s] * dis[d];
    float4 v = *reinterpret_cast<const float4*>(h2 + (size_t)s * N_CLASS + c * 4);
    float* o = xout + (size_t)d * N_CLASS + c * 4;
    atomicAdd(o + 0, v.x * norm);
    atomicAdd(o + 1, v.y * norm);
    atomicAdd(o + 2, v.z * norm);
    atomicAdd(o + 3, v.w * norm);
}

// ---------------- log_softmax (one wave per row) ----------------
__global__ __launch_bounds__(256) void logsoftmax_kernel(const float* __restrict__ xo,
                                                         float* __restrict__ out) {
    int wave = threadIdx.x >> 6;
    int lane = threadIdx.x & 63;
    int r = blockIdx.x * 4 + wave;
    if (r >= N_NODES) return;
    const float* row = xo + (size_t)r * N_CLASS;
    float v = (lane < N_CLASS) ? row[lane] : -INFINITY;
    float m = v;
#pragma unroll
    for (int o = 32; o > 0; o >>= 1) m = fmaxf(m, __shfl_xor(m, o));
    float e = (lane < N_CLASS) ? expf(v - m) : 0.0f;
    float sum = e;
#pragma unroll
    for (int o = 32; o > 0; o >>= 1) sum += __shfl_xor(sum, o);
    if (lane < N_CLASS) out[(size_t)r * N_CLASS + lane] = v - m - logf(sum);
}

extern "C" void kernel_launch(void* const* d_in, const int* in_sizes, int n_in,
                              void* d_out, int out_size, void* d_ws, size_t ws_size,
                              hipStream_t stream) {
    const float* x  = (const float*)d_in[0];
    const EIdx*  ei = (const EIdx*)d_in[1];
    const float* W1 = (const float*)d_in[2];
    const float* b1 = (const float*)d_in[3];
    const float* W2 = (const float*)d_in[4];
    const float* b2 = (const float*)d_in[5];
    const EIdx* src = ei;
    const EIdx* dst = ei + N_EDGES;

    float* out_ls  = (float*)d_out;                 // [N, 40] log_softmax
    float* x_out   = out_ls + (size_t)N_NODES * N_CLASS;  // [N, 40]

    float* ws   = (float*)d_ws;
    float* dis  = ws;                                // N (deg -> rsqrt in place)
    float* h1   = ws + 100352;                       // N*64
    float* agg1 = h1 + (size_t)N_NODES * HIDDEN;     // N*64 (then relu'd in place)
    float* h2   = agg1 + (size_t)N_NODES * HIDDEN;   // N*40

    const int B = 256;
    int gN   = (N_NODES + B - 1) / B;                // 391
    int gE   = (N_EDGES + B - 1) / B;                // 12500
    int gN16 = (N_NODES * 16) / B;                   // 6250 (exact)
    int gE16 = (N_EDGES / B) * 16;                   // 200000 (exact)
    int gN10 = (N_NODES * 10 + B - 1) / B;           // 3907
    int gE10 = (N_EDGES / B) * 10;                   // 125000 (exact)
    int gLS  = N_NODES / 4;                          // 25000 (exact)

    init_deg_kernel<<<gN, B, 0, stream>>>(dis);
    deg_count_kernel<<<gE, B, 0, stream>>>(dst, dis);
    rsqrt_kernel<<<gN, B, 0, stream>>>(dis);

    gemm1_kernel<<<gN, B, 0, stream>>>(x, W1, h1);
    agg1_init_kernel<<<gN16, B, 0, stream>>>(h1, dis, agg1);
    agg1_edge_kernel<<<gE16, B, 0, stream>>>(h1, src, dst, dis, agg1);
    relu_bias_kernel<<<gN16, B, 0, stream>>>(agg1, b1);

    gemm2_kernel<<<gN, B, 0, stream>>>(agg1, W2, h2);
    agg2_init_kernel<<<gN10, B, 0, stream>>>(h2, dis, b2, x_out);
    agg2_edge_kernel<<<gE10, B, 0, stream>>>(h2, src, dst, dis, x_out);

    logsoftmax_kernel<<<gLS, B, 0, stream>>>(x_out, out_ls);
}

// Round 2
// 875.686 us; speedup vs baseline: 5.9107x; 5.9107x over previous
//
#include <hip/hip_runtime.h>
#include <math.h>

#define N_NODES 100000
#define F_IN    512
#define HIDDEN  64
#define N_CLASS 40
#define N_EDGES 3200000

typedef int EIdx;

// ---------------- CSR build ----------------
__global__ __launch_bounds__(256) void zero_cnt_kernel(int* __restrict__ cnt) {
    int i = blockIdx.x * 256 + threadIdx.x;
    if (i < N_NODES) cnt[i] = 0;
}

__global__ __launch_bounds__(256) void deg_count_kernel(const EIdx* __restrict__ dst,
                                                        int* __restrict__ cnt) {
    int e = blockIdx.x * 256 + threadIdx.x;
    if (e < N_EDGES) atomicAdd(&cnt[dst[e]], 1);
}

__global__ __launch_bounds__(256) void dis_kernel(const int* __restrict__ cnt,
                                                  float* __restrict__ dis) {
    int i = blockIdx.x * 256 + threadIdx.x;
    if (i < N_NODES) dis[i] = rsqrtf((float)(cnt[i] + 1));  // +1 self-loop
}

// block-level exclusive scan; writes excl into rowptr, block total into bsum
__global__ __launch_bounds__(256) void scan1_kernel(const int* __restrict__ cnt,
                                                    int* __restrict__ rowptr,
                                                    int* __restrict__ bsum) {
    __shared__ int s[256];
    int t = threadIdx.x;
    int i = blockIdx.x * 256 + t;
    int v = (i < N_NODES) ? cnt[i] : 0;
    s[t] = v;
    __syncthreads();
    for (int off = 1; off < 256; off <<= 1) {
        int a = (t >= off) ? s[t - off] : 0;
        __syncthreads();
        s[t] += a;
        __syncthreads();
    }
    if (i < N_NODES) rowptr[i] = s[t] - v;  // exclusive
    if (t == 255) bsum[blockIdx.x] = s[255];
}

// scan the 391 block sums (single block)
__global__ __launch_bounds__(512) void scan2_kernel(const int* __restrict__ bsum,
                                                    int* __restrict__ bsumS, int nb) {
    __shared__ int s[512];
    int t = threadIdx.x;
    int v = (t < nb) ? bsum[t] : 0;
    s[t] = v;
    __syncthreads();
    for (int off = 1; off < 512; off <<= 1) {
        int a = (t >= off) ? s[t - off] : 0;
        __syncthreads();
        s[t] += a;
        __syncthreads();
    }
    if (t < nb) bsumS[t] = s[t] - v;  // exclusive
}

__global__ __launch_bounds__(256) void scan3_kernel(int* __restrict__ rowptr,
                                                    int* __restrict__ cursor,
                                                    const int* __restrict__ bsumS) {
    int i = blockIdx.x * 256 + threadIdx.x;
    if (i < N_NODES) {
        int r = rowptr[i] + bsumS[blockIdx.x];
        rowptr[i] = r;
        cursor[i] = r;
    }
    if (i == 0) rowptr[N_NODES] = N_EDGES;
}

__global__ __launch_bounds__(256) void fill_kernel(const EIdx* __restrict__ src,
                                                   const EIdx* __restrict__ dst,
                                                   const float* __restrict__ dis,
                                                   int* __restrict__ cursor,
                                                   int* __restrict__ csr_src,
                                                   float* __restrict__ csr_w) {
    int e = blockIdx.x * 256 + threadIdx.x;
    if (e >= N_EDGES) return;
    int s = src[e], d = dst[e];
    int pos = atomicAdd(&cursor[d], 1);
    csr_src[pos] = s;
    csr_w[pos] = dis[s] * dis[d];
}

// ---------------- GEMM1: h = x @ W1  (one row per thread) ----------------
__global__ __launch_bounds__(256) void gemm1_kernel(const float* __restrict__ x,
                                                    const float* __restrict__ W,
                                                    float* __restrict__ h) {
    int r = blockIdx.x * 256 + threadIdx.x;
    if (r >= N_NODES) return;
    float acc[HIDDEN];
#pragma unroll
    for (int j = 0; j < HIDDEN; ++j) acc[j] = 0.0f;
    const float* xr = x + (size_t)r * F_IN;
    for (int k0 = 0; k0 < F_IN; k0 += 4) {
        float4 xv = *reinterpret_cast<const float4*>(xr + k0);
        const float* wk = W + (size_t)k0 * HIDDEN;
#pragma unroll
        for (int j = 0; j < HIDDEN; ++j) {
            acc[j] = fmaf(xv.x, wk[j], acc[j]);
            acc[j] = fmaf(xv.y, wk[HIDDEN + j], acc[j]);
            acc[j] = fmaf(xv.z, wk[2 * HIDDEN + j], acc[j]);
            acc[j] = fmaf(xv.w, wk[3 * HIDDEN + j], acc[j]);
        }
    }
    float* hr = h + (size_t)r * HIDDEN;
#pragma unroll
    for (int j = 0; j < HIDDEN; j += 4) {
        float4 o = {acc[j], acc[j + 1], acc[j + 2], acc[j + 3]};
        *reinterpret_cast<float4*>(hr + j) = o;
    }
}

// ---------------- layer-1 gather: one wave per node, lane = feature ----------------
__global__ __launch_bounds__(256) void gather1_kernel(const float* __restrict__ h,
                                                      const int* __restrict__ rowptr,
                                                      const int* __restrict__ csr_src,
                                                      const float* __restrict__ csr_w,
                                                      const float* __restrict__ dis,
                                                      const float* __restrict__ b,
                                                      float* __restrict__ out) {
    int n = blockIdx.x * 4 + (threadIdx.x >> 6);   // grid covers N_NODES exactly
    int lane = threadIdx.x & 63;
    float dn = dis[n];
    float acc = h[(size_t)n * HIDDEN + lane] * dn * dn;  // self-loop
    int i = rowptr[n], i1 = rowptr[n + 1];
    for (; i + 3 < i1; i += 4) {
        int s0 = csr_src[i], s1 = csr_src[i + 1], s2 = csr_src[i + 2], s3 = csr_src[i + 3];
        float w0 = csr_w[i], w1 = csr_w[i + 1], w2 = csr_w[i + 2], w3 = csr_w[i + 3];
        float v0 = h[(size_t)s0 * HIDDEN + lane];
        float v1 = h[(size_t)s1 * HIDDEN + lane];
        float v2 = h[(size_t)s2 * HIDDEN + lane];
        float v3 = h[(size_t)s3 * HIDDEN + lane];
        acc = fmaf(v0, w0, acc);
        acc = fmaf(v1, w1, acc);
        acc = fmaf(v2, w2, acc);
        acc = fmaf(v3, w3, acc);
    }
    for (; i < i1; ++i) {
        int s = csr_src[i];
        acc = fmaf(h[(size_t)s * HIDDEN + lane], csr_w[i], acc);
    }
    out[(size_t)n * HIDDEN + lane] = fmaxf(acc + b[lane], 0.0f);  // bias + relu fused
}

// ---------------- GEMM2: h2 = out1 @ W2 (one row per thread) ----------------
__global__ __launch_bounds__(256) void gemm2_kernel(const float* __restrict__ x,
                                                    const float* __restrict__ W,
                                                    float* __restrict__ h) {
    int r = blockIdx.x * 256 + threadIdx.x;
    if (r >= N_NODES) return;
    float acc[N_CLASS];
#pragma unroll
    for (int j = 0; j < N_CLASS; ++j) acc[j] = 0.0f;
    const float* xr = x + (size_t)r * HIDDEN;
    for (int k0 = 0; k0 < HIDDEN; k0 += 4) {
        float4 xv = *reinterpret_cast<const float4*>(xr + k0);
        const float* wk = W + (size_t)k0 * N_CLASS;
#pragma unroll
        for (int j = 0; j < N_CLASS; ++j) {
            acc[j] = fmaf(xv.x, wk[j], acc[j]);
            acc[j] = fmaf(xv.y, wk[N_CLASS + j], acc[j]);
            acc[j] = fmaf(xv.z, wk[2 * N_CLASS + j], acc[j]);
            acc[j] = fmaf(xv.w, wk[3 * N_CLASS + j], acc[j]);
        }
    }
    float* hr = h + (size_t)r * N_CLASS;
#pragma unroll
    for (int j = 0; j < N_CLASS; j += 4) {
        float4 o = {acc[j], acc[j + 1], acc[j + 2], acc[j + 3]};
        *reinterpret_cast<float4*>(hr + j) = o;
    }
}

// ---------------- layer-2 gather: one wave per node, lanes 0..39 ----------------
__global__ __launch_bounds__(256) void gather2_kernel(const float* __restrict__ h,
                                                      const int* __restrict__ rowptr,
                                                      const int* __restrict__ csr_src,
                                                      const float* __restrict__ csr_w,
                                                      const float* __restrict__ dis,
                                                      const float* __restrict__ b,
                                                      float* __restrict__ out) {
    int n = blockIdx.x * 4 + (threadIdx.x >> 6);
    int lane = threadIdx.x & 63;
    int cl = (lane < N_CLASS) ? lane : (N_CLASS - 1);  // clamp: lanes 40-63 compute garbage
    float dn = dis[n];
    float acc = h[(size_t)n * N_CLASS + cl] * dn * dn;
    int i = rowptr[n], i1 = rowptr[n + 1];
    for (; i + 3 < i1; i += 4) {
        int s0 = csr_src[i], s1 = csr_src[i + 1], s2 = csr_src[i + 2], s3 = csr_src[i + 3];
        float w0 = csr_w[i], w1 = csr_w[i + 1], w2 = csr_w[i + 2], w3 = csr_w[i + 3];
        float v0 = h[(size_t)s0 * N_CLASS + cl];
        float v1 = h[(size_t)s1 * N_CLASS + cl];
        float v2 = h[(size_t)s2 * N_CLASS + cl];
        float v3 = h[(size_t)s3 * N_CLASS + cl];
        acc = fmaf(v0, w0, acc);
        acc = fmaf(v1, w1, acc);
        acc = fmaf(v2, w2, acc);
        acc = fmaf(v3, w3, acc);
    }
    for (; i < i1; ++i) {
        int s = csr_src[i];
        acc = fmaf(h[(size_t)s * N_CLASS + cl], csr_w[i], acc);
    }
    if (lane < N_CLASS) out[(size_t)n * N_CLASS + lane] = acc + b[lane];
}

// ---------------- log_softmax (one wave per row) ----------------
__global__ __launch_bounds__(256) void logsoftmax_kernel(const float* __restrict__ xo,
                                                         float* __restrict__ out) {
    int wave = threadIdx.x >> 6;
    int lane = threadIdx.x & 63;
    int r = blockIdx.x * 4 + wave;
    if (r >= N_NODES) return;
    const float* row = xo + (size_t)r * N_CLASS;
    float v = (lane < N_CLASS) ? row[lane] : -INFINITY;
    float m = v;
#pragma unroll
    for (int o = 32; o > 0; o >>= 1) m = fmaxf(m, __shfl_xor(m, o));
    float e = (lane < N_CLASS) ? expf(v - m) : 0.0f;
    float sum = e;
#pragma unroll
    for (int o = 32; o > 0; o >>= 1) sum += __shfl_xor(sum, o);
    if (lane < N_CLASS) out[(size_t)r * N_CLASS + lane] = v - m - logf(sum);
}

extern "C" void kernel_launch(void* const* d_in, const int* in_sizes, int n_in,
                              void* d_out, int out_size, void* d_ws, size_t ws_size,
                              hipStream_t stream) {
    const float* x  = (const float*)d_in[0];
    const EIdx*  ei = (const EIdx*)d_in[1];
    const float* W1 = (const float*)d_in[2];
    const float* b1 = (const float*)d_in[3];
    const float* W2 = (const float*)d_in[4];
    const float* b2 = (const float*)d_in[5];
    const EIdx* src = ei;
    const EIdx* dst = ei + N_EDGES;

    float* out_ls = (float*)d_out;                        // [N, 40] log_softmax
    float* x_out  = out_ls + (size_t)N_NODES * N_CLASS;   // [N, 40]

    // workspace carve-up (all 1KB-aligned, ~94 MB total)
    char* w = (char*)d_ws;
    const size_t NA = 100352;  // N rounded up
    int*   cnt     = (int*)w;                     w += NA * 4;
    float* dis     = (float*)w;                   w += NA * 4;
    int*   rowptr  = (int*)w;                     w += (NA + 1024) * 4;
    int*   cursor  = (int*)w;                     w += NA * 4;
    int*   bsum    = (int*)w;                     w += 1024 * 4;
    int*   bsumS   = (int*)w;                     w += 1024 * 4;
    int*   csr_src = (int*)w;                     w += (size_t)N_EDGES * 4;
    float* csr_w   = (float*)w;                   w += (size_t)N_EDGES * 4;
    float* h1      = (float*)w;                   w += (size_t)N_NODES * HIDDEN * 4;
    float* agg1    = (float*)w;                   w += (size_t)N_NODES * HIDDEN * 4;
    float* h2      = (float*)w;                   w += (size_t)N_NODES * N_CLASS * 4;

    const int B = 256;
    int gN  = (N_NODES + B - 1) / B;   // 391
    int gE  = (N_EDGES + B - 1) / B;   // 12500
    int gW  = N_NODES / 4;             // 25000 (wave per node, exact)

    // CSR build
    zero_cnt_kernel<<<gN, B, 0, stream>>>(cnt);
    deg_count_kernel<<<gE, B, 0, stream>>>(dst, cnt);
    dis_kernel<<<gN, B, 0, stream>>>(cnt, dis);
    scan1_kernel<<<gN, B, 0, stream>>>(cnt, rowptr, bsum);
    scan2_kernel<<<1, 512, 0, stream>>>(bsum, bsumS, gN);
    scan3_kernel<<<gN, B, 0, stream>>>(rowptr, cursor, bsumS);
    fill_kernel<<<gE, B, 0, stream>>>(src, dst, dis, cursor, csr_src, csr_w);

    // layer 1
    gemm1_kernel<<<gN, B, 0, stream>>>(x, W1, h1);
    gather1_kernel<<<gW, B, 0, stream>>>(h1, rowptr, csr_src, csr_w, dis, b1, agg1);

    // layer 2
    gemm2_kernel<<<gN, B, 0, stream>>>(agg1, W2, h2);
    gather2_kernel<<<gW, B, 0, stream>>>(h2, rowptr, csr_src, csr_w, dis, b2, x_out);

    logsoftmax_kernel<<<gW, B, 0, stream>>>(x_out, out_ls);
}

// Round 3
// 713.509 us; speedup vs baseline: 7.2541x; 1.2273x over previous
//
#include <hip/hip_runtime.h>
#include <math.h>

#define N_NODES 100000
#define F_IN    512
#define HIDDEN  64
#define N_CLASS 40
#define N_EDGES 3200000

typedef int EIdx;

typedef __attribute__((ext_vector_type(8))) short short8;
typedef __attribute__((ext_vector_type(4))) float f32x4;

__device__ inline short f2bf(float f) {
    unsigned u = __builtin_bit_cast(unsigned, f);
    unsigned r = u + 0x7FFFu + ((u >> 16) & 1u);   // round-to-nearest-even
    return (short)(r >> 16);
}

// ---------------- CSR build ----------------
__global__ __launch_bounds__(256) void zero_cnt_kernel(int* __restrict__ cnt) {
    int i = blockIdx.x * 256 + threadIdx.x;
    if (i < N_NODES) cnt[i] = 0;
}

__global__ __launch_bounds__(256) void deg_count_kernel(const EIdx* __restrict__ dst,
                                                        int* __restrict__ cnt) {
    int e = blockIdx.x * 256 + threadIdx.x;
    if (e < N_EDGES) atomicAdd(&cnt[dst[e]], 1);
}

__global__ __launch_bounds__(256) void dis_kernel(const int* __restrict__ cnt,
                                                  float* __restrict__ dis) {
    int i = blockIdx.x * 256 + threadIdx.x;
    if (i < N_NODES) dis[i] = rsqrtf((float)(cnt[i] + 1));  // +1 self-loop
}

__global__ __launch_bounds__(256) void scan1_kernel(const int* __restrict__ cnt,
                                                    int* __restrict__ rowptr,
                                                    int* __restrict__ bsum) {
    __shared__ int s[256];
    int t = threadIdx.x;
    int i = blockIdx.x * 256 + t;
    int v = (i < N_NODES) ? cnt[i] : 0;
    s[t] = v;
    __syncthreads();
    for (int off = 1; off < 256; off <<= 1) {
        int a = (t >= off) ? s[t - off] : 0;
        __syncthreads();
        s[t] += a;
        __syncthreads();
    }
    if (i < N_NODES) rowptr[i] = s[t] - v;  // exclusive
    if (t == 255) bsum[blockIdx.x] = s[255];
}

__global__ __launch_bounds__(512) void scan2_kernel(const int* __restrict__ bsum,
                                                    int* __restrict__ bsumS, int nb) {
    __shared__ int s[512];
    int t = threadIdx.x;
    int v = (t < nb) ? bsum[t] : 0;
    s[t] = v;
    __syncthreads();
    for (int off = 1; off < 512; off <<= 1) {
        int a = (t >= off) ? s[t - off] : 0;
        __syncthreads();
        s[t] += a;
        __syncthreads();
    }
    if (t < nb) bsumS[t] = s[t] - v;  // exclusive
}

__global__ __launch_bounds__(256) void scan3_kernel(int* __restrict__ rowptr,
                                                    int* __restrict__ cursor,
                                                    const int* __restrict__ bsumS) {
    int i = blockIdx.x * 256 + threadIdx.x;
    if (i < N_NODES) {
        int r = rowptr[i] + bsumS[blockIdx.x];
        rowptr[i] = r;
        cursor[i] = r;
    }
    if (i == 0) rowptr[N_NODES] = N_EDGES;
}

__global__ __launch_bounds__(256) void fill_kernel(const EIdx* __restrict__ src,
                                                   const EIdx* __restrict__ dst,
                                                   const float* __restrict__ dis,
                                                   int* __restrict__ cursor,
                                                   int* __restrict__ csr_src,
                                                   float* __restrict__ csr_w) {
    int e = blockIdx.x * 256 + threadIdx.x;
    if (e >= N_EDGES) return;
    int s = src[e], d = dst[e];
    int pos = atomicAdd(&cursor[d], 1);
    csr_src[pos] = s;
    csr_w[pos] = dis[s] * dis[d];
}

// ---------------- GEMM1 (MFMA bf16): h = x @ W1 ----------------
// block = 256 thr (4 waves); wave computes 32 rows x 64 cols; BM = 128 rows/block.
// W staged to LDS as bf16, transposed [col][k], XOR-swizzled (k ^= (col&7)<<3).
__global__ __launch_bounds__(256) void gemm1_mfma_kernel(const float* __restrict__ x,
                                                         const float* __restrict__ W,
                                                         float* __restrict__ h) {
    __shared__ short Wt[HIDDEN * F_IN];  // 64 KiB
    int tid = threadIdx.x;
    for (int idx = tid; idx < F_IN * HIDDEN; idx += 256) {
        int k = idx >> 6, col = idx & 63;            // W is [k][col], read coalesced
        Wt[col * F_IN + (k ^ ((col & 7) << 3))] = f2bf(W[idx]);
    }
    __syncthreads();

    int wave = tid >> 6, lane = tid & 63;
    int r0 = blockIdx.x * 128 + wave * 32;
    int lrow = lane & 15;
    int lk = (lane >> 4) * 8;      // k-offset of this lane's 8-element fragment

    f32x4 acc[2][4];
#pragma unroll
    for (int m = 0; m < 2; ++m)
#pragma unroll
        for (int n = 0; n < 4; ++n) acc[m][n] = (f32x4)0.0f;

    int rowA0 = r0 + lrow;       if (rowA0 >= N_NODES) rowA0 = N_NODES - 1;
    int rowA1 = r0 + 16 + lrow;  if (rowA1 >= N_NODES) rowA1 = N_NODES - 1;
    const float* pA0 = x + (size_t)rowA0 * F_IN + lk;
    const float* pA1 = x + (size_t)rowA1 * F_IN + lk;

    // B fragment LDS short-index bases (k0 varies in loop); col&7 == lane&7 since n*16%8==0
    int bswz = (lane & 7) << 3;

    for (int k0 = 0; k0 < F_IN; k0 += 32) {
        short8 a0, a1;
        {
            float4 v0 = *reinterpret_cast<const float4*>(pA0 + k0);
            float4 v1 = *reinterpret_cast<const float4*>(pA0 + k0 + 4);
            a0[0] = f2bf(v0.x); a0[1] = f2bf(v0.y); a0[2] = f2bf(v0.z); a0[3] = f2bf(v0.w);
            a0[4] = f2bf(v1.x); a0[5] = f2bf(v1.y); a0[6] = f2bf(v1.z); a0[7] = f2bf(v1.w);
        }
        {
            float4 v0 = *reinterpret_cast<const float4*>(pA1 + k0);
            float4 v1 = *reinterpret_cast<const float4*>(pA1 + k0 + 4);
            a1[0] = f2bf(v0.x); a1[1] = f2bf(v0.y); a1[2] = f2bf(v0.z); a1[3] = f2bf(v0.w);
            a1[4] = f2bf(v1.x); a1[5] = f2bf(v1.y); a1[6] = f2bf(v1.z); a1[7] = f2bf(v1.w);
        }
        short8 b[4];
#pragma unroll
        for (int n = 0; n < 4; ++n) {
            int c = n * 16 + lrow;
            int si = c * F_IN + ((k0 + lk) ^ bswz);
            b[n] = *reinterpret_cast<const short8*>(&Wt[si]);
        }
#pragma unroll
        for (int n = 0; n < 4; ++n) {
            acc[0][n] = __builtin_amdgcn_mfma_f32_16x16x32_bf16(a0, b[n], acc[0][n], 0, 0, 0);
            acc[1][n] = __builtin_amdgcn_mfma_f32_16x16x32_bf16(a1, b[n], acc[1][n], 0, 0, 0);
        }
    }

    // C layout: col = lane&15, row = (lane>>4)*4 + reg
    int crow = (lane >> 4) * 4, ccol = lane & 15;
#pragma unroll
    for (int m = 0; m < 2; ++m) {
        int rbase = r0 + m * 16 + crow;
#pragma unroll
        for (int n = 0; n < 4; ++n) {
#pragma unroll
            for (int j = 0; j < 4; ++j) {
                int rr = rbase + j;
                if (rr < N_NODES) h[(size_t)rr * HIDDEN + n * 16 + ccol] = acc[m][n][j];
            }
        }
    }
}

// ---------------- layer-1 gather: one wave per node, lane = feature ----------------
__global__ __launch_bounds__(256) void gather1_kernel(const float* __restrict__ h,
                                                      const int* __restrict__ rowptr,
                                                      const int* __restrict__ csr_src,
                                                      const float* __restrict__ csr_w,
                                                      const float* __restrict__ dis,
                                                      const float* __restrict__ b,
                                                      float* __restrict__ out) {
    int n = blockIdx.x * 4 + (threadIdx.x >> 6);
    int lane = threadIdx.x & 63;
    float dn = dis[n];
    float acc = h[(size_t)n * HIDDEN + lane] * dn * dn;  // self-loop
    int i = rowptr[n], i1 = rowptr[n + 1];
    for (; i + 3 < i1; i += 4) {
        int s0 = csr_src[i], s1 = csr_src[i + 1], s2 = csr_src[i + 2], s3 = csr_src[i + 3];
        float w0 = csr_w[i], w1 = csr_w[i + 1], w2 = csr_w[i + 2], w3 = csr_w[i + 3];
        float v0 = h[(size_t)s0 * HIDDEN + lane];
        float v1 = h[(size_t)s1 * HIDDEN + lane];
        float v2 = h[(size_t)s2 * HIDDEN + lane];
        float v3 = h[(size_t)s3 * HIDDEN + lane];
        acc = fmaf(v0, w0, acc);
        acc = fmaf(v1, w1, acc);
        acc = fmaf(v2, w2, acc);
        acc = fmaf(v3, w3, acc);
    }
    for (; i < i1; ++i) {
        int s = csr_src[i];
        acc = fmaf(h[(size_t)s * HIDDEN + lane], csr_w[i], acc);
    }
    out[(size_t)n * HIDDEN + lane] = fmaxf(acc + b[lane], 0.0f);  // bias + relu fused
}

// ---------------- GEMM2: h2 = out1 @ W2 (one row per thread) ----------------
__global__ __launch_bounds__(256) void gemm2_kernel(const float* __restrict__ x,
                                                    const float* __restrict__ W,
                                                    float* __restrict__ h) {
    int r = blockIdx.x * 256 + threadIdx.x;
    if (r >= N_NODES) return;
    float acc[N_CLASS];
#pragma unroll
    for (int j = 0; j < N_CLASS; ++j) acc[j] = 0.0f;
    const float* xr = x + (size_t)r * HIDDEN;
    for (int k0 = 0; k0 < HIDDEN; k0 += 4) {
        float4 xv = *reinterpret_cast<const float4*>(xr + k0);
        const float* wk = W + (size_t)k0 * N_CLASS;
#pragma unroll
        for (int j = 0; j < N_CLASS; ++j) {
            acc[j] = fmaf(xv.x, wk[j], acc[j]);
            acc[j] = fmaf(xv.y, wk[N_CLASS + j], acc[j]);
            acc[j] = fmaf(xv.z, wk[2 * N_CLASS + j], acc[j]);
            acc[j] = fmaf(xv.w, wk[3 * N_CLASS + j], acc[j]);
        }
    }
    float* hr = h + (size_t)r * N_CLASS;
#pragma unroll
    for (int j = 0; j < N_CLASS; j += 4) {
        float4 o = {acc[j], acc[j + 1], acc[j + 2], acc[j + 3]};
        *reinterpret_cast<float4*>(hr + j) = o;
    }
}

// ---------------- layer-2 gather: one wave per node, lanes 0..39 ----------------
__global__ __launch_bounds__(256) void gather2_kernel(const float* __restrict__ h,
                                                      const int* __restrict__ rowptr,
                                                      const int* __restrict__ csr_src,
                                                      const float* __restrict__ csr_w,
                                                      const float* __restrict__ dis,
                                                      const float* __restrict__ b,
                                                      float* __restrict__ out) {
    int n = blockIdx.x * 4 + (threadIdx.x >> 6);
    int lane = threadIdx.x & 63;
    int cl = (lane < N_CLASS) ? lane : (N_CLASS - 1);
    float dn = dis[n];
    float acc = h[(size_t)n * N_CLASS + cl] * dn * dn;
    int i = rowptr[n], i1 = rowptr[n + 1];
    for (; i + 3 < i1; i += 4) {
        int s0 = csr_src[i], s1 = csr_src[i + 1], s2 = csr_src[i + 2], s3 = csr_src[i + 3];
        float w0 = csr_w[i], w1 = csr_w[i + 1], w2 = csr_w[i + 2], w3 = csr_w[i + 3];
        float v0 = h[(size_t)s0 * N_CLASS + cl];
        float v1 = h[(size_t)s1 * N_CLASS + cl];
        float v2 = h[(size_t)s2 * N_CLASS + cl];
        float v3 = h[(size_t)s3 * N_CLASS + cl];
        acc = fmaf(v0, w0, acc);
        acc = fmaf(v1, w1, acc);
        acc = fmaf(v2, w2, acc);
        acc = fmaf(v3, w3, acc);
    }
    for (; i < i1; ++i) {
        int s = csr_src[i];
        acc = fmaf(h[(size_t)s * N_CLASS + cl], csr_w[i], acc);
    }
    if (lane < N_CLASS) out[(size_t)n * N_CLASS + lane] = acc + b[lane];
}

// ---------------- log_softmax (one wave per row) ----------------
__global__ __launch_bounds__(256) void logsoftmax_kernel(const float* __restrict__ xo,
                                                         float* __restrict__ out) {
    int wave = threadIdx.x >> 6;
    int lane = threadIdx.x & 63;
    int r = blockIdx.x * 4 + wave;
    if (r >= N_NODES) return;
    const float* row = xo + (size_t)r * N_CLASS;
    float v = (lane < N_CLASS) ? row[lane] : -INFINITY;
    float m = v;
#pragma unroll
    for (int o = 32; o > 0; o >>= 1) m = fmaxf(m, __shfl_xor(m, o));
    float e = (lane < N_CLASS) ? expf(v - m) : 0.0f;
    float sum = e;
#pragma unroll
    for (int o = 32; o > 0; o >>= 1) sum += __shfl_xor(sum, o);
    if (lane < N_CLASS) out[(size_t)r * N_CLASS + lane] = v - m - logf(sum);
}

extern "C" void kernel_launch(void* const* d_in, const int* in_sizes, int n_in,
                              void* d_out, int out_size, void* d_ws, size_t ws_size,
                              hipStream_t stream) {
    const float* x  = (const float*)d_in[0];
    const EIdx*  ei = (const EIdx*)d_in[1];
    const float* W1 = (const float*)d_in[2];
    const float* b1 = (const float*)d_in[3];
    const float* W2 = (const float*)d_in[4];
    const float* b2 = (const float*)d_in[5];
    const EIdx* src = ei;
    const EIdx* dst = ei + N_EDGES;

    float* out_ls = (float*)d_out;                        // [N, 40] log_softmax
    float* x_out  = out_ls + (size_t)N_NODES * N_CLASS;   // [N, 40]

    char* w = (char*)d_ws;
    const size_t NA = 100352;
    int*   cnt     = (int*)w;                     w += NA * 4;
    float* dis     = (float*)w;                   w += NA * 4;
    int*   rowptr  = (int*)w;                     w += (NA + 1024) * 4;
    int*   cursor  = (int*)w;                     w += NA * 4;
    int*   bsum    = (int*)w;                     w += 1024 * 4;
    int*   bsumS   = (int*)w;                     w += 1024 * 4;
    int*   csr_src = (int*)w;                     w += (size_t)N_EDGES * 4;
    float* csr_w   = (float*)w;                   w += (size_t)N_EDGES * 4;
    float* h1      = (float*)w;                   w += (size_t)N_NODES * HIDDEN * 4;
    float* agg1    = (float*)w;                   w += (size_t)N_NODES * HIDDEN * 4;
    float* h2      = (float*)w;                   w += (size_t)N_NODES * N_CLASS * 4;

    const int B = 256;
    int gN  = (N_NODES + B - 1) / B;     // 391
    int gE  = (N_EDGES + B - 1) / B;     // 12500
    int gW  = N_NODES / 4;               // 25000
    int gM1 = (N_NODES + 127) / 128;     // 782

    // CSR build
    zero_cnt_kernel<<<gN, B, 0, stream>>>(cnt);
    deg_count_kernel<<<gE, B, 0, stream>>>(dst, cnt);
    dis_kernel<<<gN, B, 0, stream>>>(cnt, dis);
    scan1_kernel<<<gN, B, 0, stream>>>(cnt, rowptr, bsum);
    scan2_kernel<<<1, 512, 0, stream>>>(bsum, bsumS, gN);
    scan3_kernel<<<gN, B, 0, stream>>>(rowptr, cursor, bsumS);
    fill_kernel<<<gE, B, 0, stream>>>(src, dst, dis, cursor, csr_src, csr_w);

    // layer 1
    gemm1_mfma_kernel<<<gM1, B, 0, stream>>>(x, W1, h1);
    gather1_kernel<<<gW, B, 0, stream>>>(h1, rowptr, csr_src, csr_w, dis, b1, agg1);

    // layer 2
    gemm2_kernel<<<gN, B, 0, stream>>>(agg1, W2, h2);
    gather2_kernel<<<gW, B, 0, stream>>>(h2, rowptr, csr_src, csr_w, dis, b2, x_out);

    logsoftmax_kernel<<<gW, B, 0, stream>>>(x_out, out_ls);
}

// Round 4
// 707.854 us; speedup vs baseline: 7.3121x; 1.0080x over previous
//
#include <hip/hip_runtime.h>
#include <math.h>

#define N_NODES 100000
#define F_IN    512
#define HIDDEN  64
#define N_CLASS 40
#define N_EDGES 3200000

typedef int EIdx;

typedef __attribute__((ext_vector_type(8))) short short8;
typedef __attribute__((ext_vector_type(4))) float f32x4;

__device__ inline short f2bf(float f) {
    unsigned u = __builtin_bit_cast(unsigned, f);
    unsigned r = u + 0x7FFFu + ((u >> 16) & 1u);   // round-to-nearest-even
    return (short)(r >> 16);
}

// ---------------- CSR build ----------------
__global__ __launch_bounds__(256) void zero_cnt_kernel(int* __restrict__ cnt) {
    int i = blockIdx.x * 256 + threadIdx.x;
    if (i < N_NODES) cnt[i] = 0;
}

__global__ __launch_bounds__(256) void deg_count_kernel(const EIdx* __restrict__ dst,
                                                        int* __restrict__ cnt) {
    int e = blockIdx.x * 256 + threadIdx.x;
    if (e < N_EDGES) atomicAdd(&cnt[dst[e]], 1);
}

__global__ __launch_bounds__(256) void dis_kernel(const int* __restrict__ cnt,
                                                  float* __restrict__ dis) {
    int i = blockIdx.x * 256 + threadIdx.x;
    if (i < N_NODES) dis[i] = rsqrtf((float)(cnt[i] + 1));  // +1 self-loop
}

__global__ __launch_bounds__(256) void scan1_kernel(const int* __restrict__ cnt,
                                                    int* __restrict__ rowptr,
                                                    int* __restrict__ bsum) {
    __shared__ int s[256];
    int t = threadIdx.x;
    int i = blockIdx.x * 256 + t;
    int v = (i < N_NODES) ? cnt[i] : 0;
    s[t] = v;
    __syncthreads();
    for (int off = 1; off < 256; off <<= 1) {
        int a = (t >= off) ? s[t - off] : 0;
        __syncthreads();
        s[t] += a;
        __syncthreads();
    }
    if (i < N_NODES) rowptr[i] = s[t] - v;  // exclusive
    if (t == 255) bsum[blockIdx.x] = s[255];
}

__global__ __launch_bounds__(512) void scan2_kernel(const int* __restrict__ bsum,
                                                    int* __restrict__ bsumS, int nb) {
    __shared__ int s[512];
    int t = threadIdx.x;
    int v = (t < nb) ? bsum[t] : 0;
    s[t] = v;
    __syncthreads();
    for (int off = 1; off < 512; off <<= 1) {
        int a = (t >= off) ? s[t - off] : 0;
        __syncthreads();
        s[t] += a;
        __syncthreads();
    }
    if (t < nb) bsumS[t] = s[t] - v;  // exclusive
}

__global__ __launch_bounds__(256) void scan3_kernel(int* __restrict__ rowptr,
                                                    int* __restrict__ cursor,
                                                    const int* __restrict__ bsumS) {
    int i = blockIdx.x * 256 + threadIdx.x;
    if (i < N_NODES) {
        int r = rowptr[i] + bsumS[blockIdx.x];
        rowptr[i] = r;
        cursor[i] = r;
    }
    if (i == 0) rowptr[N_NODES] = N_EDGES;
}

// fill: only csr_src (weights are factored into row scaling, see gemm epilogues)
__global__ __launch_bounds__(256) void fill_kernel(const EIdx* __restrict__ src,
                                                   const EIdx* __restrict__ dst,
                                                   int* __restrict__ cursor,
                                                   int* __restrict__ csr_src) {
    int e = blockIdx.x * 256 + threadIdx.x;
    if (e >= N_EDGES) return;
    int s = src[e], d = dst[e];
    int pos = atomicAdd(&cursor[d], 1);
    csr_src[pos] = s;
}

// ---------------- GEMM1 (MFMA bf16): h' = (x @ W1) * dis[row] ----------------
__global__ __launch_bounds__(256) void gemm1_mfma_kernel(const float* __restrict__ x,
                                                         const float* __restrict__ W,
                                                         const float* __restrict__ dis,
                                                         float* __restrict__ h) {
    __shared__ short Wt[HIDDEN * F_IN];  // 64 KiB
    int tid = threadIdx.x;
    for (int idx = tid; idx < F_IN * HIDDEN; idx += 256) {
        int k = idx >> 6, col = idx & 63;            // W is [k][col], read coalesced
        Wt[col * F_IN + (k ^ ((col & 7) << 3))] = f2bf(W[idx]);
    }
    __syncthreads();

    int wave = tid >> 6, lane = tid & 63;
    int r0 = blockIdx.x * 128 + wave * 32;
    int lrow = lane & 15;
    int lk = (lane >> 4) * 8;

    f32x4 acc[2][4];
#pragma unroll
    for (int m = 0; m < 2; ++m)
#pragma unroll
        for (int n = 0; n < 4; ++n) acc[m][n] = (f32x4)0.0f;

    int rowA0 = r0 + lrow;       if (rowA0 >= N_NODES) rowA0 = N_NODES - 1;
    int rowA1 = r0 + 16 + lrow;  if (rowA1 >= N_NODES) rowA1 = N_NODES - 1;
    const float* pA0 = x + (size_t)rowA0 * F_IN + lk;
    const float* pA1 = x + (size_t)rowA1 * F_IN + lk;

    int bswz = (lane & 7) << 3;

    for (int k0 = 0; k0 < F_IN; k0 += 32) {
        short8 a0, a1;
        {
            float4 v0 = *reinterpret_cast<const float4*>(pA0 + k0);
            float4 v1 = *reinterpret_cast<const float4*>(pA0 + k0 + 4);
            a0[0] = f2bf(v0.x); a0[1] = f2bf(v0.y); a0[2] = f2bf(v0.z); a0[3] = f2bf(v0.w);
            a0[4] = f2bf(v1.x); a0[5] = f2bf(v1.y); a0[6] = f2bf(v1.z); a0[7] = f2bf(v1.w);
        }
        {
            float4 v0 = *reinterpret_cast<const float4*>(pA1 + k0);
            float4 v1 = *reinterpret_cast<const float4*>(pA1 + k0 + 4);
            a1[0] = f2bf(v0.x); a1[1] = f2bf(v0.y); a1[2] = f2bf(v0.z); a1[3] = f2bf(v0.w);
            a1[4] = f2bf(v1.x); a1[5] = f2bf(v1.y); a1[6] = f2bf(v1.z); a1[7] = f2bf(v1.w);
        }
        short8 b[4];
#pragma unroll
        for (int n = 0; n < 4; ++n) {
            int c = n * 16 + lrow;
            int si = c * F_IN + ((k0 + lk) ^ bswz);
            b[n] = *reinterpret_cast<const short8*>(&Wt[si]);
        }
#pragma unroll
        for (int n = 0; n < 4; ++n) {
            acc[0][n] = __builtin_amdgcn_mfma_f32_16x16x32_bf16(a0, b[n], acc[0][n], 0, 0, 0);
            acc[1][n] = __builtin_amdgcn_mfma_f32_16x16x32_bf16(a1, b[n], acc[1][n], 0, 0, 0);
        }
    }

    // C layout: col = lane&15, row = (lane>>4)*4 + reg; scale row by dis[row]
    int crow = (lane >> 4) * 4, ccol = lane & 15;
#pragma unroll
    for (int m = 0; m < 2; ++m) {
        int rbase = r0 + m * 16 + crow;
#pragma unroll
        for (int j = 0; j < 4; ++j) {
            int rr = rbase + j;
            if (rr < N_NODES) {
                float ds = dis[rr];
#pragma unroll
                for (int n = 0; n < 4; ++n)
                    h[(size_t)rr * HIDDEN + n * 16 + ccol] = acc[m][n][j] * ds;
            }
        }
    }
}

// ---------------- layer-1 gather: acc = h'[n] + sum h'[s]; out = relu(acc*dis[n]+b) ----------------
__global__ __launch_bounds__(256) void gather1_kernel(const float* __restrict__ h,
                                                      const int* __restrict__ rowptr,
                                                      const int* __restrict__ csr_src,
                                                      const float* __restrict__ dis,
                                                      const float* __restrict__ b,
                                                      float* __restrict__ out) {
    int n = blockIdx.x * 4 + (threadIdx.x >> 6);
    int lane = threadIdx.x & 63;
    float acc = h[(size_t)n * HIDDEN + lane];   // self-loop (pre-scaled by dis[n])
    int i = rowptr[n], i1 = rowptr[n + 1];
    for (; i + 3 < i1; i += 4) {
        int s0 = csr_src[i], s1 = csr_src[i + 1], s2 = csr_src[i + 2], s3 = csr_src[i + 3];
        float v0 = h[(size_t)s0 * HIDDEN + lane];
        float v1 = h[(size_t)s1 * HIDDEN + lane];
        float v2 = h[(size_t)s2 * HIDDEN + lane];
        float v3 = h[(size_t)s3 * HIDDEN + lane];
        acc += (v0 + v1) + (v2 + v3);
    }
    for (; i < i1; ++i) acc += h[(size_t)csr_src[i] * HIDDEN + lane];
    out[(size_t)n * HIDDEN + lane] = fmaxf(fmaf(acc, dis[n], b[lane]), 0.0f);
}

// ---------------- GEMM2: h2' = (out1 @ W2) * dis[row] (one row per thread) ----------------
__global__ __launch_bounds__(256) void gemm2_kernel(const float* __restrict__ x,
                                                    const float* __restrict__ W,
                                                    const float* __restrict__ dis,
                                                    float* __restrict__ h) {
    int r = blockIdx.x * 256 + threadIdx.x;
    if (r >= N_NODES) return;
    float acc[N_CLASS];
#pragma unroll
    for (int j = 0; j < N_CLASS; ++j) acc[j] = 0.0f;
    const float* xr = x + (size_t)r * HIDDEN;
    for (int k0 = 0; k0 < HIDDEN; k0 += 4) {
        float4 xv = *reinterpret_cast<const float4*>(xr + k0);
        const float* wk = W + (size_t)k0 * N_CLASS;
#pragma unroll
        for (int j = 0; j < N_CLASS; ++j) {
            acc[j] = fmaf(xv.x, wk[j], acc[j]);
            acc[j] = fmaf(xv.y, wk[N_CLASS + j], acc[j]);
            acc[j] = fmaf(xv.z, wk[2 * N_CLASS + j], acc[j]);
            acc[j] = fmaf(xv.w, wk[3 * N_CLASS + j], acc[j]);
        }
    }
    float ds = dis[r];
    float* hr = h + (size_t)r * N_CLASS;
#pragma unroll
    for (int j = 0; j < N_CLASS; j += 4) {
        float4 o = {acc[j] * ds, acc[j + 1] * ds, acc[j + 2] * ds, acc[j + 3] * ds};
        *reinterpret_cast<float4*>(hr + j) = o;
    }
}

// ---------------- layer-2 gather + fused log_softmax ----------------
__global__ __launch_bounds__(256) void gather2_kernel(const float* __restrict__ h,
                                                      const int* __restrict__ rowptr,
                                                      const int* __restrict__ csr_src,
                                                      const float* __restrict__ dis,
                                                      const float* __restrict__ b,
                                                      float* __restrict__ xout,
                                                      float* __restrict__ out_ls) {
    int n = blockIdx.x * 4 + (threadIdx.x >> 6);
    int lane = threadIdx.x & 63;
    int cl = (lane < N_CLASS) ? lane : (N_CLASS - 1);  // clamped for loads
    float acc = h[(size_t)n * N_CLASS + cl];            // self-loop (pre-scaled)
    int i = rowptr[n], i1 = rowptr[n + 1];
    for (; i + 3 < i1; i += 4) {
        int s0 = csr_src[i], s1 = csr_src[i + 1], s2 = csr_src[i + 2], s3 = csr_src[i + 3];
        float v0 = h[(size_t)s0 * N_CLASS + cl];
        float v1 = h[(size_t)s1 * N_CLASS + cl];
        float v2 = h[(size_t)s2 * N_CLASS + cl];
        float v3 = h[(size_t)s3 * N_CLASS + cl];
        acc += (v0 + v1) + (v2 + v3);
    }
    for (; i < i1; ++i) acc += h[(size_t)csr_src[i] * N_CLASS + cl];

    float v = fmaf(acc, dis[n], b[cl]);
    float vr = (lane < N_CLASS) ? v : -INFINITY;
    float m = vr;
#pragma unroll
    for (int o = 32; o > 0; o >>= 1) m = fmaxf(m, __shfl_xor(m, o));
    float e = (lane < N_CLASS) ? expf(v - m) : 0.0f;
    float sum = e;
#pragma unroll
    for (int o = 32; o > 0; o >>= 1) sum += __shfl_xor(sum, o);
    if (lane < N_CLASS) {
        xout[(size_t)n * N_CLASS + lane] = v;
        out_ls[(size_t)n * N_CLASS + lane] = v - m - logf(sum);
    }
}

extern "C" void kernel_launch(void* const* d_in, const int* in_sizes, int n_in,
                              void* d_out, int out_size, void* d_ws, size_t ws_size,
                              hipStream_t stream) {
    const float* x  = (const float*)d_in[0];
    const EIdx*  ei = (const EIdx*)d_in[1];
    const float* W1 = (const float*)d_in[2];
    const float* b1 = (const float*)d_in[3];
    const float* W2 = (const float*)d_in[4];
    const float* b2 = (const float*)d_in[5];
    const EIdx* src = ei;
    const EIdx* dst = ei + N_EDGES;

    float* out_ls = (float*)d_out;                        // [N, 40] log_softmax
    float* x_out  = out_ls + (size_t)N_NODES * N_CLASS;   // [N, 40]

    char* w = (char*)d_ws;
    const size_t NA = 100352;
    int*   cnt     = (int*)w;                     w += NA * 4;
    float* dis     = (float*)w;                   w += NA * 4;
    int*   rowptr  = (int*)w;                     w += (NA + 1024) * 4;
    int*   cursor  = (int*)w;                     w += NA * 4;
    int*   bsum    = (int*)w;                     w += 1024 * 4;
    int*   bsumS   = (int*)w;                     w += 1024 * 4;
    int*   csr_src = (int*)w;                     w += (size_t)N_EDGES * 4;
    float* h1      = (float*)w;                   w += (size_t)N_NODES * HIDDEN * 4;
    float* agg1    = (float*)w;                   w += (size_t)N_NODES * HIDDEN * 4;
    float* h2      = (float*)w;                   w += (size_t)N_NODES * N_CLASS * 4;

    const int B = 256;
    int gN  = (N_NODES + B - 1) / B;     // 391
    int gE  = (N_EDGES + B - 1) / B;     // 12500
    int gW  = N_NODES / 4;               // 25000
    int gM1 = (N_NODES + 127) / 128;     // 782

    // CSR build
    zero_cnt_kernel<<<gN, B, 0, stream>>>(cnt);
    deg_count_kernel<<<gE, B, 0, stream>>>(dst, cnt);
    dis_kernel<<<gN, B, 0, stream>>>(cnt, dis);
    scan1_kernel<<<gN, B, 0, stream>>>(cnt, rowptr, bsum);
    scan2_kernel<<<1, 512, 0, stream>>>(bsum, bsumS, gN);
    scan3_kernel<<<gN, B, 0, stream>>>(rowptr, cursor, bsumS);
    fill_kernel<<<gE, B, 0, stream>>>(src, dst, cursor, csr_src);

    // layer 1
    gemm1_mfma_kernel<<<gM1, B, 0, stream>>>(x, W1, dis, h1);
    gather1_kernel<<<gW, B, 0, stream>>>(h1, rowptr, csr_src, dis, b1, agg1);

    // layer 2
    gemm2_kernel<<<gN, B, 0, stream>>>(agg1, W2, dis, h2);
    gather2_kernel<<<gW, B, 0, stream>>>(h2, rowptr, csr_src, dis, b2, x_out, out_ls);
}